// Round 1
// baseline (5043.429 us; speedup 1.0000x reference)
//
#include <hip/hip_runtime.h>

#define S 4096
#define D 2048
#define NH 16
#define HD 128

// ---------------- GEMM: Y[m,n] = sum_k X[m,k] * W[n,k]  (nn.Linear, NT) ----
#define GM 64
#define GN 64
#define GK 32

__global__ __launch_bounds__(256) void gemm_nt_kernel(
    const float* __restrict__ X,
    const float* __restrict__ W0, const float* __restrict__ W1, const float* __restrict__ W2,
    float* __restrict__ Y0, float* __restrict__ Y1, float* __restrict__ Y2)
{
    const int z = blockIdx.z;
    const float* __restrict__ W = (z == 0) ? W0 : (z == 1) ? W1 : W2;
    float* __restrict__ Y = (z == 0) ? Y0 : (z == 1) ? Y1 : Y2;

    __shared__ float Xs[GK][GM + 4];   // Xs[k][m]
    __shared__ float Ws[GK][GN + 4];   // Ws[k][n]

    const int tid = threadIdx.x;
    const int tx = tid & 15;
    const int ty = tid >> 4;
    const int m0 = blockIdx.y * GM;
    const int n0 = blockIdx.x * GN;

    float acc[4][4] = {};

    for (int k0 = 0; k0 < D; k0 += GK) {
        #pragma unroll
        for (int it = 0; it < 2; ++it) {
            int idx = tid + it * 256;          // 0..511
            int r = idx >> 3;                  // 0..63
            int c4 = (idx & 7) << 2;           // 0,4,..,28
            float4 xv = *(const float4*)&X[(size_t)(m0 + r) * D + k0 + c4];
            Xs[c4 + 0][r] = xv.x; Xs[c4 + 1][r] = xv.y;
            Xs[c4 + 2][r] = xv.z; Xs[c4 + 3][r] = xv.w;
            float4 wv = *(const float4*)&W[(size_t)(n0 + r) * D + k0 + c4];
            Ws[c4 + 0][r] = wv.x; Ws[c4 + 1][r] = wv.y;
            Ws[c4 + 2][r] = wv.z; Ws[c4 + 3][r] = wv.w;
        }
        __syncthreads();
        #pragma unroll
        for (int kk = 0; kk < GK; ++kk) {
            float4 a = *(const float4*)&Xs[kk][ty * 4];
            float4 b = *(const float4*)&Ws[kk][tx * 4];
            float ae[4] = {a.x, a.y, a.z, a.w};
            float be[4] = {b.x, b.y, b.z, b.w};
            #pragma unroll
            for (int i = 0; i < 4; ++i)
                #pragma unroll
                for (int j = 0; j < 4; ++j)
                    acc[i][j] = fmaf(ae[i], be[j], acc[i][j]);
        }
        __syncthreads();
    }

    #pragma unroll
    for (int i = 0; i < 4; ++i) {
        float4 o = make_float4(acc[i][0], acc[i][1], acc[i][2], acc[i][3]);
        *(float4*)&Y[(size_t)(m0 + ty * 4 + i) * D + n0 + tx * 4] = o;
    }
}

// ---------------- RMSNorm over head_dim=128, per (s, h) row ----------------
__global__ __launch_bounds__(256) void rmsnorm_kernel(
    float* __restrict__ Q, float* __restrict__ K,
    const float* __restrict__ qw, const float* __restrict__ kw)
{
    float* P = (blockIdx.y == 0) ? Q : K;
    const float* w = (blockIdx.y == 0) ? qw : kw;
    const int wid = threadIdx.x >> 6;        // wave in block (0..3)
    const int lane = threadIdx.x & 63;
    const size_t row = (size_t)blockIdx.x * 4 + wid;  // 0..65535 rows of 128

    float2 v = *(float2*)&P[row * HD + lane * 2];
    float ss = v.x * v.x + v.y * v.y;
    #pragma unroll
    for (int off = 1; off < 64; off <<= 1) ss += __shfl_xor(ss, off, 64);
    float sc = 1.0f / sqrtf(ss * (1.0f / HD) + 1e-6f);
    float2 wv = *(const float2*)&w[lane * 2];
    v.x *= sc * wv.x;
    v.y *= sc * wv.y;
    *(float2*)&P[row * HD + lane * 2] = v;
}

// ---------------- Flash attention, fp32, BQ=BK=64 --------------------------
// Og may alias Qg (each block writes exactly the region only it reads).
__global__ __launch_bounds__(256) void flash_kernel(
    const float* Qg, const float* __restrict__ Kg,
    const float* __restrict__ Vg, float* Og)
{
    __shared__ float Qs[64][HD + 4];     // Qs[q][d], pre-scaled
    __shared__ float Kt[HD][64 + 4];     // Kt[d][k]  (transposed)
    __shared__ float Vs[64][HD + 4];     // Vs[k][d]
    __shared__ float Sc[64][64 + 4];     // scores -> probabilities
    __shared__ float mrow[64], lrow[64], arow[64];

    const int tid = threadIdx.x;
    const int tx = tid & 15;
    const int ty = tid >> 4;
    const int q0 = blockIdx.x * 64;
    const size_t hoff = (size_t)blockIdx.y * HD;
    const float scale = 0.08838834764831845f;  // 1/sqrt(128)

    #pragma unroll
    for (int it = 0; it < 8; ++it) {
        int idx = tid + it * 256;          // 2048 float4 slots
        int r = idx >> 5;                  // 0..63
        int c4 = (idx & 31) << 2;          // 0..124
        float4 qv = *(const float4*)&Qg[(size_t)(q0 + r) * D + hoff + c4];
        qv.x *= scale; qv.y *= scale; qv.z *= scale; qv.w *= scale;
        *(float4*)&Qs[r][c4] = qv;
    }
    if (tid < 64) { mrow[tid] = -1e30f; lrow[tid] = 0.0f; }

    float o[4][8] = {};

    for (int j0 = 0; j0 < S; j0 += 64) {
        __syncthreads();
        #pragma unroll
        for (int it = 0; it < 8; ++it) {
            int idx = tid + it * 256;
            int r = idx >> 5;
            int c4 = (idx & 31) << 2;
            float4 kv = *(const float4*)&Kg[(size_t)(j0 + r) * D + hoff + c4];
            Kt[c4 + 0][r] = kv.x; Kt[c4 + 1][r] = kv.y;
            Kt[c4 + 2][r] = kv.z; Kt[c4 + 3][r] = kv.w;
            *(float4*)&Vs[r][c4] = *(const float4*)&Vg[(size_t)(j0 + r) * D + hoff + c4];
        }
        __syncthreads();

        // scores: rows 4ty+i, cols 4tx+j (outer-product over d)
        float s[4][4] = {};
        #pragma unroll 8
        for (int d = 0; d < HD; ++d) {
            float4 b = *(const float4*)&Kt[d][tx * 4];
            float be[4] = {b.x, b.y, b.z, b.w};
            #pragma unroll
            for (int i = 0; i < 4; ++i) {
                float a = Qs[ty * 4 + i][d];
                #pragma unroll
                for (int j = 0; j < 4; ++j)
                    s[i][j] = fmaf(a, be[j], s[i][j]);
            }
        }
        #pragma unroll
        for (int i = 0; i < 4; ++i)
            *(float4*)&Sc[ty * 4 + i][tx * 4] =
                make_float4(s[i][0], s[i][1], s[i][2], s[i][3]);
        __syncthreads();

        // online softmax, one thread per query row
        if (tid < 64) {
            const int r = tid;
            float mold = mrow[r];
            float mnew = mold;
            for (int c = 0; c < 64; ++c) mnew = fmaxf(mnew, Sc[r][c]);
            float alpha = __expf(mold - mnew);
            float l = lrow[r] * alpha;
            for (int c = 0; c < 64; ++c) {
                float p = __expf(Sc[r][c] - mnew);
                Sc[r][c] = p;
                l += p;
            }
            mrow[r] = mnew; lrow[r] = l; arow[r] = alpha;
        }
        __syncthreads();

        // rescale O, then O += P @ V ; thread covers rows 4ty+i, cols 8tx..+7
        #pragma unroll
        for (int i = 0; i < 4; ++i) {
            float al = arow[ty * 4 + i];
            #pragma unroll
            for (int c = 0; c < 8; ++c) o[i][c] *= al;
        }
        #pragma unroll 4
        for (int j = 0; j < 64; ++j) {
            float4 v0 = *(const float4*)&Vs[j][tx * 8];
            float4 v1 = *(const float4*)&Vs[j][tx * 8 + 4];
            #pragma unroll
            for (int i = 0; i < 4; ++i) {
                float p = Sc[ty * 4 + i][j];
                o[i][0] = fmaf(p, v0.x, o[i][0]);
                o[i][1] = fmaf(p, v0.y, o[i][1]);
                o[i][2] = fmaf(p, v0.z, o[i][2]);
                o[i][3] = fmaf(p, v0.w, o[i][3]);
                o[i][4] = fmaf(p, v1.x, o[i][4]);
                o[i][5] = fmaf(p, v1.y, o[i][5]);
                o[i][6] = fmaf(p, v1.z, o[i][6]);
                o[i][7] = fmaf(p, v1.w, o[i][7]);
            }
        }
    }

    #pragma unroll
    for (int i = 0; i < 4; ++i) {
        float linv = 1.0f / lrow[ty * 4 + i];
        float4 r0 = make_float4(o[i][0] * linv, o[i][1] * linv,
                                o[i][2] * linv, o[i][3] * linv);
        float4 r1 = make_float4(o[i][4] * linv, o[i][5] * linv,
                                o[i][6] * linv, o[i][7] * linv);
        *(float4*)&Og[(size_t)(q0 + ty * 4 + i) * D + hoff + tx * 8] = r0;
        *(float4*)&Og[(size_t)(q0 + ty * 4 + i) * D + hoff + tx * 8 + 4] = r1;
    }
}

extern "C" void kernel_launch(void* const* d_in, const int* in_sizes, int n_in,
                              void* d_out, int out_size, void* d_ws, size_t ws_size,
                              hipStream_t stream)
{
    const float* x  = (const float*)d_in[0];
    const float* wq = (const float*)d_in[1];
    const float* wk = (const float*)d_in[2];
    const float* wv = (const float*)d_in[3];
    const float* wo = (const float*)d_in[4];
    const float* qw = (const float*)d_in[5];
    const float* kw = (const float*)d_in[6];
    float* out = (float*)d_out;

    float* Q = (float*)d_ws;                 // [S, D]; later reused as context
    float* K = Q + (size_t)S * D;            // [S, D]
    float* V = K + (size_t)S * D;            // [S, D]

    // Q/K/V projections (z selects weight/output)
    dim3 gp(D / GN, S / GM, 3);
    gemm_nt_kernel<<<gp, dim3(256), 0, stream>>>(x, wq, wk, wv, Q, K, V);

    // RMSNorm on Q and K (65536 rows of 128 each; 4 waves/block, y = tensor)
    rmsnorm_kernel<<<dim3(S * NH / 4, 2), dim3(256), 0, stream>>>(Q, K, qw, kw);

    // Flash attention; context overwrites Q buffer (block-private regions)
    flash_kernel<<<dim3(S / 64, NH), dim3(256), 0, stream>>>(Q, K, V, Q);

    // Output projection: out = context @ wo^T
    dim3 go(D / GN, S / GM, 1);
    gemm_nt_kernel<<<go, dim3(256), 0, stream>>>(Q, wo, wo, wo, out, out, out);
}

// Round 2
// 703.466 us; speedup vs baseline: 7.1694x; 7.1694x over previous
//
#include <hip/hip_runtime.h>
#include <hip/hip_bf16.h>

#define S 4096
#define D 2048
#define NH 16
#define HD 128

typedef __attribute__((ext_vector_type(8))) short bf16x8;
typedef __attribute__((ext_vector_type(4))) float f32x4;

typedef __attribute__((address_space(1))) char glob_char;
typedef __attribute__((address_space(3))) char lds_char_t;

__device__ __forceinline__ void gld16(const void* g, void* l) {
    __builtin_amdgcn_global_load_lds((const glob_char*)g, (lds_char_t*)l, 16, 0, 0);
}

__device__ __forceinline__ unsigned short f2b(float f) {
    union { float f; unsigned u; } c; c.f = f;
    unsigned r = c.u + 0x7fff + ((c.u >> 16) & 1);
    return (unsigned short)(r >> 16);
}
__device__ __forceinline__ float b2f(unsigned short u) {
    union { unsigned u; float f; } c; c.u = ((unsigned)u) << 16;
    return c.f;
}

// ---------------- fp32 -> bf16 conversion --------------------------------
__global__ __launch_bounds__(256) void cvt_bf16(const float* __restrict__ src,
                                                unsigned short* __restrict__ dst, int n4) {
    int i = blockIdx.x * 256 + threadIdx.x;
    if (i < n4) {
        float4 v = ((const float4*)src)[i];
        ushort4 o;
        o.x = f2b(v.x); o.y = f2b(v.y); o.z = f2b(v.z); o.w = f2b(v.w);
        ((ushort4*)dst)[i] = o;
    }
}

// ---------------- bf16 NT GEMM (m97 structure): C = A @ B^T --------------
// A [M][2048], B [N][2048] bf16 row-major.  OUTMODE 0: bf16 out split by
// n>>11 into O0/O1/O2 (each [M][2048]); OUTMODE 1: fp32 out to O0 [M][2048].
template<int OUTMODE>
__global__ __launch_bounds__(256) void gemm_nt(
    const unsigned short* __restrict__ A, const unsigned short* __restrict__ B,
    void* __restrict__ O0, void* __restrict__ O1, void* __restrict__ O2)
{
    __shared__ short As[128 * 32];
    __shared__ short Bs[128 * 32];

    const int tid = threadIdx.x;
    const int m0 = blockIdx.y * 128, n0 = blockIdx.x * 128;
    const int w = tid >> 6, lane = tid & 63, col = lane & 15, quad = lane >> 4;
    const int mw = (w >> 1) * 64, nw = (w & 1) * 64;

    const int r0 = tid >> 2, k80 = (tid & 3) << 3;
    const size_t aoff = (size_t)(m0 + r0) * 2048 + k80;
    const size_t boff = (size_t)(n0 + r0) * 2048 + k80;

    f32x4 acc[4][4];
    #pragma unroll
    for (int i = 0; i < 4; ++i)
        #pragma unroll
        for (int j = 0; j < 4; ++j)
            #pragma unroll
            for (int r = 0; r < 4; ++r) acc[i][j][r] = 0.0f;

    for (int k0 = 0; k0 < 2048; k0 += 32) {
        gld16(&A[aoff + k0],               &As[tid * 8]);
        gld16(&A[aoff + 64 * 2048 + k0],   &As[(tid + 256) * 8]);
        gld16(&B[boff + k0],               &Bs[tid * 8]);
        gld16(&B[boff + 64 * 2048 + k0],   &Bs[(tid + 256) * 8]);
        __syncthreads();
        bf16x8 af[4], bf[4];
        #pragma unroll
        for (int i = 0; i < 4; ++i)
            af[i] = *(const bf16x8*)&As[(mw + 16 * i + col) * 32 + quad * 8];
        #pragma unroll
        for (int j = 0; j < 4; ++j)
            bf[j] = *(const bf16x8*)&Bs[(nw + 16 * j + col) * 32 + quad * 8];
        #pragma unroll
        for (int i = 0; i < 4; ++i)
            #pragma unroll
            for (int j = 0; j < 4; ++j)
                acc[i][j] = __builtin_amdgcn_mfma_f32_16x16x32_bf16(af[i], bf[j], acc[i][j], 0, 0, 0);
        __syncthreads();
    }

    if (OUTMODE == 1) {
        float* C = (float*)O0;
        #pragma unroll
        for (int i = 0; i < 4; ++i)
            #pragma unroll
            for (int j = 0; j < 4; ++j)
                #pragma unroll
                for (int r = 0; r < 4; ++r)
                    C[(size_t)(m0 + mw + 16 * i + quad * 4 + r) * 2048 + n0 + nw + 16 * j + col] = acc[i][j][r];
    } else {
        const int sel = n0 >> 11;
        unsigned short* C = (unsigned short*)(sel == 0 ? O0 : sel == 1 ? O1 : O2);
        const int nc0 = (n0 & 2047) + nw + col;
        #pragma unroll
        for (int i = 0; i < 4; ++i)
            #pragma unroll
            for (int j = 0; j < 4; ++j)
                #pragma unroll
                for (int r = 0; r < 4; ++r)
                    C[(size_t)(m0 + mw + 16 * i + quad * 4 + r) * 2048 + nc0 + 16 * j] = f2b(acc[i][j][r]);
    }
}

// ---------------- RMSNorm on bf16 Q/K rows of 128; Q gets 1/sqrt(HD) -----
__global__ __launch_bounds__(256) void rmsnorm_qk(
    unsigned short* __restrict__ Q, unsigned short* __restrict__ K,
    const float* __restrict__ qw, const float* __restrict__ kw)
{
    const int wid = threadIdx.x >> 6, lane = threadIdx.x & 63;
    const int row = blockIdx.x * 4 + wid;     // 0..65535
    const int s = row >> 4, h = row & 15;
    const bool isQ = (blockIdx.y == 0);
    unsigned short* P = isQ ? Q : K;
    const float* wgt = isQ ? qw : kw;
    const float extra = isQ ? 0.08838834764831845f : 1.0f;

    const size_t off = (size_t)s * 2048 + h * 128 + lane * 2;
    ushort2 u = *(const ushort2*)&P[off];
    float a = b2f(u.x), b = b2f(u.y);
    float ss = a * a + b * b;
    #pragma unroll
    for (int d = 1; d < 64; d <<= 1) ss += __shfl_xor(ss, d, 64);
    float sc = rsqrtf(ss * (1.0f / HD) + 1e-6f) * extra;
    ushort2 o;
    o.x = f2b(a * sc * wgt[lane * 2]);
    o.y = f2b(b * sc * wgt[lane * 2 + 1]);
    *(ushort2*)&P[off] = o;
}

// ---------------- V transpose: V[s][2048] -> Vt[h][dv][s] ----------------
__global__ __launch_bounds__(256) void transpose_v(
    const unsigned short* __restrict__ V, unsigned short* __restrict__ Vt)
{
    __shared__ short T[64][80];   // padded: row stride 160 B (16B aligned)
    const int tid = threadIdx.x;
    const int c0 = blockIdx.x * 64, r0 = blockIdx.y * 64;

    #pragma unroll
    for (int it = 0; it < 2; ++it) {
        int idx = tid + (it << 8);
        int r = idx >> 3, c8 = (idx & 7) << 3;
        *(bf16x8*)&T[r][c8] = *(const bf16x8*)&V[(size_t)(r0 + r) * 2048 + c0 + c8];
    }
    __syncthreads();
    #pragma unroll
    for (int it = 0; it < 2; ++it) {
        int cc = tid & 63, sg = (tid >> 6) + (it << 2);
        int colg = c0 + cc;
        int h = colg >> 7, dv = colg & 127;
        short tmp[8];
        #pragma unroll
        for (int j = 0; j < 8; ++j) tmp[j] = T[sg * 8 + j][cc];
        *(bf16x8*)&Vt[(size_t)h * (HD * S) + (size_t)dv * S + r0 + sg * 8] = *(const bf16x8*)tmp;
    }
}

// ---------------- MFMA flash attention, BQ=64, BK=64 ---------------------
__global__ __launch_bounds__(256) void flash_mfma(
    const unsigned short* __restrict__ Qg, const unsigned short* __restrict__ Kg,
    const unsigned short* __restrict__ Vt, unsigned short* __restrict__ Ctx)
{
    __shared__ short Qs[4 * 64 * 32];   // [dstep][q][dk]
    __shared__ short Ks[4 * 64 * 32];   // [dstep][kidx][dk]
    __shared__ short Vs[2 * 128 * 32];  // [kstep][dv][kk]
    __shared__ short Ps[4 * 16 * 72];   // per-wave [q][72] (padded)

    const int tid = threadIdx.x;
    const int w = tid >> 6, lane = tid & 63, col = lane & 15, quad = lane >> 4;
    const int q0 = blockIdx.x * 64, h = blockIdx.y;

    // stage Q (16 KB)
    #pragma unroll
    for (int it = 0; it < 4; ++it) {
        int c = tid + (it << 8);
        int ds = c >> 8, rem = c & 255, row = rem >> 2, k8 = (rem & 3) << 3;
        gld16(&Qg[(size_t)(q0 + row) * 2048 + h * 128 + ds * 32 + k8], &Qs[c * 8]);
    }

    float m_r[4], l_r[4];
    #pragma unroll
    for (int r = 0; r < 4; ++r) { m_r[r] = -1e30f; l_r[r] = 0.0f; }
    f32x4 o[8];
    #pragma unroll
    for (int nj = 0; nj < 8; ++nj)
        #pragma unroll
        for (int r = 0; r < 4; ++r) o[nj][r] = 0.0f;

    for (int j0 = 0; j0 < S; j0 += 64) {
        __syncthreads();   // previous iteration's LDS reads done
        #pragma unroll
        for (int it = 0; it < 4; ++it) {
            int c = tid + (it << 8);
            int ds = c >> 8, rem = c & 255, row = rem >> 2, k8 = (rem & 3) << 3;
            gld16(&Kg[(size_t)(j0 + row) * 2048 + h * 128 + ds * 32 + k8], &Ks[c * 8]);
        }
        #pragma unroll
        for (int it = 0; it < 4; ++it) {
            int c = tid + (it << 8);
            int ks = c >> 9, rem = c & 511, dv = rem >> 2, k8 = (rem & 3) << 3;
            gld16(&Vt[(size_t)h * (HD * S) + (size_t)dv * S + j0 + ks * 32 + k8], &Vs[c * 8]);
        }
        __syncthreads();

        // scores: S[q][kidx], wave's 16 q rows x 64 kidx
        f32x4 sc[4];
        #pragma unroll
        for (int kj = 0; kj < 4; ++kj)
            #pragma unroll
            for (int r = 0; r < 4; ++r) sc[kj][r] = 0.0f;
        #pragma unroll
        for (int ds = 0; ds < 4; ++ds) {
            bf16x8 aq = *(const bf16x8*)&Qs[(ds * 64 + w * 16 + col) * 32 + quad * 8];
            #pragma unroll
            for (int kj = 0; kj < 4; ++kj) {
                bf16x8 bk = *(const bf16x8*)&Ks[(ds * 64 + kj * 16 + col) * 32 + quad * 8];
                sc[kj] = __builtin_amdgcn_mfma_f32_16x16x32_bf16(aq, bk, sc[kj], 0, 0, 0);
            }
        }

        // online softmax (C layout: row q%16 = quad*4+r, col = kj*16+col)
        float mx[4], al[4], rs[4];
        #pragma unroll
        for (int r = 0; r < 4; ++r)
            mx[r] = fmaxf(fmaxf(sc[0][r], sc[1][r]), fmaxf(sc[2][r], sc[3][r]));
        #pragma unroll
        for (int d = 1; d < 16; d <<= 1)
            #pragma unroll
            for (int r = 0; r < 4; ++r) mx[r] = fmaxf(mx[r], __shfl_xor(mx[r], d, 64));
        #pragma unroll
        for (int r = 0; r < 4; ++r) {
            float mn = fmaxf(m_r[r], mx[r]);
            al[r] = __expf(m_r[r] - mn);
            m_r[r] = mn;
            rs[r] = 0.0f;
        }
        #pragma unroll
        for (int kj = 0; kj < 4; ++kj)
            #pragma unroll
            for (int r = 0; r < 4; ++r) {
                float p = __expf(sc[kj][r] - m_r[r]);
                rs[r] += p;
                Ps[(w * 16 + quad * 4 + r) * 72 + kj * 16 + col] = (short)f2b(p);
            }
        #pragma unroll
        for (int d = 1; d < 16; d <<= 1)
            #pragma unroll
            for (int r = 0; r < 4; ++r) rs[r] += __shfl_xor(rs[r], d, 64);
        #pragma unroll
        for (int r = 0; r < 4; ++r) l_r[r] = l_r[r] * al[r] + rs[r];
        #pragma unroll
        for (int nj = 0; nj < 8; ++nj)
            #pragma unroll
            for (int r = 0; r < 4; ++r) o[nj][r] *= al[r];

        // O += P @ V   (A = Ps rows, B = Vs rows; same-wave LDS is in-order)
        #pragma unroll
        for (int ks = 0; ks < 2; ++ks) {
            bf16x8 ap = *(const bf16x8*)&Ps[(w * 16 + col) * 72 + ks * 32 + quad * 8];
            #pragma unroll
            for (int nj = 0; nj < 8; ++nj) {
                bf16x8 bv = *(const bf16x8*)&Vs[(ks * 128 + nj * 16 + col) * 32 + quad * 8];
                o[nj] = __builtin_amdgcn_mfma_f32_16x16x32_bf16(ap, bv, o[nj], 0, 0, 0);
            }
        }
    }

    #pragma unroll
    for (int r = 0; r < 4; ++r) m_r[r] = 1.0f / l_r[r];   // reuse as 1/l
    #pragma unroll
    for (int nj = 0; nj < 8; ++nj)
        #pragma unroll
        for (int r = 0; r < 4; ++r)
            Ctx[(size_t)(q0 + w * 16 + quad * 4 + r) * 2048 + h * 128 + nj * 16 + col] =
                f2b(o[nj][r] * m_r[r]);
}

extern "C" void kernel_launch(void* const* d_in, const int* in_sizes, int n_in,
                              void* d_out, int out_size, void* d_ws, size_t ws_size,
                              hipStream_t stream)
{
    const float* x  = (const float*)d_in[0];
    const float* wq = (const float*)d_in[1];
    const float* wk = (const float*)d_in[2];
    const float* wv = (const float*)d_in[3];
    const float* wo = (const float*)d_in[4];
    const float* qw = (const float*)d_in[5];
    const float* kw = (const float*)d_in[6];
    float* out = (float*)d_out;

    const size_t MB = 1u << 20;
    char* ws = (char*)d_ws;
    unsigned short* xb    = (unsigned short*)(ws);             // 16 MB; later Ctx
    unsigned short* Wqkvb = (unsigned short*)(ws + 16 * MB);   // 24 MB; later Vt
    unsigned short* Wob   = (unsigned short*)(ws + 40 * MB);   //  8 MB
    unsigned short* Qb    = (unsigned short*)(ws + 48 * MB);   // 16 MB
    unsigned short* Kb    = (unsigned short*)(ws + 64 * MB);   // 16 MB
    unsigned short* Vb    = (unsigned short*)(ws + 80 * MB);   // 16 MB
    unsigned short* Vt    = Wqkvb;                             // overlay after proj
    unsigned short* Ctx   = xb;                                // overlay after proj

    // bf16 conversions
    cvt_bf16<<<dim3(8192), dim3(256), 0, stream>>>(x, xb, (S * D) / 4);
    cvt_bf16<<<dim3(4096), dim3(256), 0, stream>>>(wq, Wqkvb,               (D * D) / 4);
    cvt_bf16<<<dim3(4096), dim3(256), 0, stream>>>(wk, Wqkvb + (size_t)D * D, (D * D) / 4);
    cvt_bf16<<<dim3(4096), dim3(256), 0, stream>>>(wv, Wqkvb + 2 * (size_t)D * D, (D * D) / 4);
    cvt_bf16<<<dim3(4096), dim3(256), 0, stream>>>(wo, Wob, (D * D) / 4);

    // fused QKV projection: [4096][6144] = xb @ Wqkvb^T  -> Qb | Kb | Vb
    gemm_nt<0><<<dim3(48, 32), dim3(256), 0, stream>>>(xb, Wqkvb, Qb, Kb, Vb);

    // RMSNorm on Q (with 1/sqrt(HD) fold) and K
    rmsnorm_qk<<<dim3(16384, 2), dim3(256), 0, stream>>>(Qb, Kb, qw, kw);

    // V -> Vt[h][dv][s]   (into the now-dead Wqkvb region)
    transpose_v<<<dim3(32, 64), dim3(256), 0, stream>>>(Vb, Vt);

    // flash attention -> Ctx bf16 [4096][2048] (into the now-dead xb region)
    flash_mfma<<<dim3(64, 16), dim3(256), 0, stream>>>(Qb, Kb, Vt, Ctx);

    // output projection: out fp32 = Ctx @ Wob^T
    gemm_nt<1><<<dim3(16, 32), dim3(256), 0, stream>>>(Ctx, Wob, out, out, out);
}

// Round 3
// 579.076 us; speedup vs baseline: 8.7094x; 1.2148x over previous
//
#include <hip/hip_runtime.h>
#include <hip/hip_bf16.h>

#define S 4096
#define D 2048
#define NH 16
#define HD 128

typedef __attribute__((ext_vector_type(8))) short bf16x8;
typedef __attribute__((ext_vector_type(4))) float f32x4;

typedef __attribute__((address_space(1))) char glob_char;
typedef __attribute__((address_space(3))) char lds_char_t;

__device__ __forceinline__ void gld16(const void* g, void* l) {
    __builtin_amdgcn_global_load_lds((const glob_char*)g, (lds_char_t*)l, 16, 0, 0);
}

__device__ __forceinline__ unsigned short f2b(float f) {
    union { float f; unsigned u; } c; c.f = f;
    unsigned r = c.u + 0x7fff + ((c.u >> 16) & 1);
    return (unsigned short)(r >> 16);
}
__device__ __forceinline__ float b2f(unsigned short u) {
    union { unsigned u; float f; } c; c.u = ((unsigned)u) << 16;
    return c.f;
}

// ---------------- fp32 -> bf16 conversion --------------------------------
__global__ __launch_bounds__(256) void cvt_bf16(const float* __restrict__ src,
                                                unsigned short* __restrict__ dst, int n4) {
    int i = blockIdx.x * 256 + threadIdx.x;
    if (i < n4) {
        float4 v = ((const float4*)src)[i];
        ushort4 o;
        o.x = f2b(v.x); o.y = f2b(v.y); o.z = f2b(v.z); o.w = f2b(v.w);
        ((ushort4*)dst)[i] = o;
    }
}

// ---------------- bf16 NT GEMM (m97 structure): C = A @ B^T --------------
template<int OUTMODE>
__global__ __launch_bounds__(256) void gemm_nt(
    const unsigned short* __restrict__ A, const unsigned short* __restrict__ B,
    void* __restrict__ O0, void* __restrict__ O1, void* __restrict__ O2)
{
    __shared__ short As[128 * 32];
    __shared__ short Bs[128 * 32];

    const int tid = threadIdx.x;
    const int m0 = blockIdx.y * 128, n0 = blockIdx.x * 128;
    const int w = tid >> 6, lane = tid & 63, col = lane & 15, quad = lane >> 4;
    const int mw = (w >> 1) * 64, nw = (w & 1) * 64;

    const int r0 = tid >> 2, k80 = (tid & 3) << 3;
    const size_t aoff = (size_t)(m0 + r0) * 2048 + k80;
    const size_t boff = (size_t)(n0 + r0) * 2048 + k80;

    f32x4 acc[4][4];
    #pragma unroll
    for (int i = 0; i < 4; ++i)
        #pragma unroll
        for (int j = 0; j < 4; ++j)
            #pragma unroll
            for (int r = 0; r < 4; ++r) acc[i][j][r] = 0.0f;

    for (int k0 = 0; k0 < 2048; k0 += 32) {
        gld16(&A[aoff + k0],               &As[tid * 8]);
        gld16(&A[aoff + 64 * 2048 + k0],   &As[(tid + 256) * 8]);
        gld16(&B[boff + k0],               &Bs[tid * 8]);
        gld16(&B[boff + 64 * 2048 + k0],   &Bs[(tid + 256) * 8]);
        __syncthreads();
        bf16x8 af[4], bf[4];
        #pragma unroll
        for (int i = 0; i < 4; ++i)
            af[i] = *(const bf16x8*)&As[(mw + 16 * i + col) * 32 + quad * 8];
        #pragma unroll
        for (int j = 0; j < 4; ++j)
            bf[j] = *(const bf16x8*)&Bs[(nw + 16 * j + col) * 32 + quad * 8];
        #pragma unroll
        for (int i = 0; i < 4; ++i)
            #pragma unroll
            for (int j = 0; j < 4; ++j)
                acc[i][j] = __builtin_amdgcn_mfma_f32_16x16x32_bf16(af[i], bf[j], acc[i][j], 0, 0, 0);
        __syncthreads();
    }

    if (OUTMODE == 1) {
        float* C = (float*)O0;
        #pragma unroll
        for (int i = 0; i < 4; ++i)
            #pragma unroll
            for (int j = 0; j < 4; ++j)
                #pragma unroll
                for (int r = 0; r < 4; ++r)
                    C[(size_t)(m0 + mw + 16 * i + quad * 4 + r) * 2048 + n0 + nw + 16 * j + col] = acc[i][j][r];
    } else {
        const int sel = n0 >> 11;
        unsigned short* C = (unsigned short*)(sel == 0 ? O0 : sel == 1 ? O1 : O2);
        const int nc0 = (n0 & 2047) + nw + col;
        #pragma unroll
        for (int i = 0; i < 4; ++i)
            #pragma unroll
            for (int j = 0; j < 4; ++j)
                #pragma unroll
                for (int r = 0; r < 4; ++r)
                    C[(size_t)(m0 + mw + 16 * i + quad * 4 + r) * 2048 + nc0 + 16 * j] = f2b(acc[i][j][r]);
    }
}

// ---------------- RMSNorm on bf16 Q/K rows of 128; Q gets 1/sqrt(HD) -----
__global__ __launch_bounds__(256) void rmsnorm_qk(
    unsigned short* __restrict__ Q, unsigned short* __restrict__ K,
    const float* __restrict__ qw, const float* __restrict__ kw)
{
    const int wid = threadIdx.x >> 6, lane = threadIdx.x & 63;
    const int row = blockIdx.x * 4 + wid;     // 0..65535
    const int s = row >> 4, h = row & 15;
    const bool isQ = (blockIdx.y == 0);
    unsigned short* P = isQ ? Q : K;
    const float* wgt = isQ ? qw : kw;
    const float extra = isQ ? 0.08838834764831845f : 1.0f;

    const size_t off = (size_t)s * 2048 + h * 128 + lane * 2;
    ushort2 u = *(const ushort2*)&P[off];
    float a = b2f(u.x), b = b2f(u.y);
    float ss = a * a + b * b;
    #pragma unroll
    for (int d = 1; d < 64; d <<= 1) ss += __shfl_xor(ss, d, 64);
    float sc = rsqrtf(ss * (1.0f / HD) + 1e-6f) * extra;
    ushort2 o;
    o.x = f2b(a * sc * wgt[lane * 2]);
    o.y = f2b(b * sc * wgt[lane * 2 + 1]);
    *(ushort2*)&P[off] = o;
}

// ---------------- V transpose: V[s][2048] -> Vt[h][dv][s] ----------------
__global__ __launch_bounds__(256) void transpose_v(
    const unsigned short* __restrict__ V, unsigned short* __restrict__ Vt)
{
    __shared__ short T[64][80];
    const int tid = threadIdx.x;
    const int c0 = blockIdx.x * 64, r0 = blockIdx.y * 64;

    #pragma unroll
    for (int it = 0; it < 2; ++it) {
        int idx = tid + (it << 8);
        int r = idx >> 3, c8 = (idx & 7) << 3;
        *(bf16x8*)&T[r][c8] = *(const bf16x8*)&V[(size_t)(r0 + r) * 2048 + c0 + c8];
    }
    __syncthreads();
    #pragma unroll
    for (int it = 0; it < 2; ++it) {
        int cc = tid & 63, sg = (tid >> 6) + (it << 2);
        int colg = c0 + cc;
        int h = colg >> 7, dv = colg & 127;
        short tmp[8];
        #pragma unroll
        for (int j = 0; j < 8; ++j) tmp[j] = T[sg * 8 + j][cc];
        *(bf16x8*)&Vt[(size_t)h * (HD * S) + (size_t)dv * S + r0 + sg * 8] = *(const bf16x8*)tmp;
    }
}

// ---------------- MFMA flash attention v2 --------------------------------
// BQ=64, BK=64, K/V double-buffered (1 barrier per tile), Q in registers,
// no-max softmax (|score| <= sqrt(128) by Cauchy-Schwarz after RMSNorm).
__global__ __launch_bounds__(256) void flash_mfma(
    const unsigned short* __restrict__ Qg, const unsigned short* __restrict__ Kg,
    const unsigned short* __restrict__ Vt, unsigned short* __restrict__ Ctx)
{
    __shared__ short Ks[2][4 * 64 * 32];    // [buf][ds][kidx][32]
    __shared__ short Vs[2][2 * 128 * 32];   // [buf][ks][dv][32]
    __shared__ short Ps[4][16 * 72];        // per-wave [q][72]

    const int tid = threadIdx.x;
    const int w = tid >> 6, lane = tid & 63, col = lane & 15, quad = lane >> 4;
    const int q0 = blockIdx.x * 64, h = blockIdx.y;
    const size_t vbase = (size_t)h * (HD * S);

    // Q fragments in registers (A-layout: row=col, k=quad*8.. per dstep)
    bf16x8 aq[4];
    {
        const size_t qoff = (size_t)(q0 + w * 16 + col) * 2048 + h * 128 + quad * 8;
        #pragma unroll
        for (int ds = 0; ds < 4; ++ds)
            aq[ds] = *(const bf16x8*)&Qg[qoff + ds * 32];
    }

    float l_r[4] = {0.0f, 0.0f, 0.0f, 0.0f};
    f32x4 o[8];
    #pragma unroll
    for (int nj = 0; nj < 8; ++nj)
        #pragma unroll
        for (int r = 0; r < 4; ++r) o[nj][r] = 0.0f;

    auto stage = [&](int j0s, int b) {
        #pragma unroll
        for (int it = 0; it < 4; ++it) {
            int c = tid + (it << 8);
            int ds = c >> 8, rem = c & 255, row = rem >> 2, k8 = (rem & 3) << 3;
            gld16(&Kg[(size_t)(j0s + row) * 2048 + h * 128 + ds * 32 + k8], &Ks[b][c * 8]);
        }
        #pragma unroll
        for (int it = 0; it < 4; ++it) {
            int c = tid + (it << 8);
            int ks = c >> 9, rem = c & 511, dv = rem >> 2, k8 = (rem & 3) << 3;
            gld16(&Vt[vbase + (size_t)dv * S + j0s + ks * 32 + k8], &Vs[b][c * 8]);
        }
    };

    auto compute = [&](int b) {
        f32x4 sc[4];
        #pragma unroll
        for (int kj = 0; kj < 4; ++kj)
            #pragma unroll
            for (int r = 0; r < 4; ++r) sc[kj][r] = 0.0f;
        #pragma unroll
        for (int ds = 0; ds < 4; ++ds) {
            #pragma unroll
            for (int kj = 0; kj < 4; ++kj) {
                bf16x8 bk = *(const bf16x8*)&Ks[b][(ds * 64 + kj * 16 + col) * 32 + quad * 8];
                sc[kj] = __builtin_amdgcn_mfma_f32_16x16x32_bf16(aq[ds], bk, sc[kj], 0, 0, 0);
            }
        }
        // p = exp(score); no max needed (|score| <= 11.32); bf16-rounded p
        // goes to both numerator (Ps) and denominator (l_r).
        #pragma unroll
        for (int kj = 0; kj < 4; ++kj)
            #pragma unroll
            for (int r = 0; r < 4; ++r) {
                unsigned short pb = f2b(__expf(sc[kj][r]));
                Ps[w][(quad * 4 + r) * 72 + kj * 16 + col] = (short)pb;
                l_r[r] += b2f(pb);
            }
        #pragma unroll
        for (int ks = 0; ks < 2; ++ks) {
            bf16x8 ap = *(const bf16x8*)&Ps[w][col * 72 + ks * 32 + quad * 8];
            #pragma unroll
            for (int nj = 0; nj < 8; ++nj) {
                bf16x8 bv = *(const bf16x8*)&Vs[b][(ks * 128 + nj * 16 + col) * 32 + quad * 8];
                o[nj] = __builtin_amdgcn_mfma_f32_16x16x32_bf16(ap, bv, o[nj], 0, 0, 0);
            }
        }
    };

    stage(0, 0);
    for (int j0 = 0; j0 < S; j0 += 128) {
        __syncthreads();                       // buf0 ready; buf1 free
        stage(j0 + 64, 1);                     // prefetch into buf1 (async)
        compute(0);
        __syncthreads();                       // buf1 ready; buf0 free
        if (j0 + 128 < S) stage(j0 + 128, 0);  // prefetch into buf0 (async)
        compute(1);
    }

    // reduce l across the 16 col-lanes of each quad
    #pragma unroll
    for (int d = 1; d < 16; d <<= 1)
        #pragma unroll
        for (int r = 0; r < 4; ++r) l_r[r] += __shfl_xor(l_r[r], d, 64);
    float inv[4];
    #pragma unroll
    for (int r = 0; r < 4; ++r) inv[r] = 1.0f / l_r[r];

    #pragma unroll
    for (int nj = 0; nj < 8; ++nj)
        #pragma unroll
        for (int r = 0; r < 4; ++r)
            Ctx[(size_t)(q0 + w * 16 + quad * 4 + r) * 2048 + h * 128 + nj * 16 + col] =
                f2b(o[nj][r] * inv[r]);
}

extern "C" void kernel_launch(void* const* d_in, const int* in_sizes, int n_in,
                              void* d_out, int out_size, void* d_ws, size_t ws_size,
                              hipStream_t stream)
{
    const float* x  = (const float*)d_in[0];
    const float* wq = (const float*)d_in[1];
    const float* wk = (const float*)d_in[2];
    const float* wv = (const float*)d_in[3];
    const float* wo = (const float*)d_in[4];
    const float* qw = (const float*)d_in[5];
    const float* kw = (const float*)d_in[6];
    float* out = (float*)d_out;

    const size_t MB = 1u << 20;
    char* ws = (char*)d_ws;
    unsigned short* xb    = (unsigned short*)(ws);             // 16 MB; later Ctx
    unsigned short* Wqkvb = (unsigned short*)(ws + 16 * MB);   // 24 MB; later Vt
    unsigned short* Wob   = (unsigned short*)(ws + 40 * MB);   //  8 MB
    unsigned short* Qb    = (unsigned short*)(ws + 48 * MB);   // 16 MB
    unsigned short* Kb    = (unsigned short*)(ws + 64 * MB);   // 16 MB
    unsigned short* Vb    = (unsigned short*)(ws + 80 * MB);   // 16 MB
    unsigned short* Vt    = Wqkvb;                             // overlay after proj
    unsigned short* Ctx   = xb;                                // overlay after proj

    cvt_bf16<<<dim3(8192), dim3(256), 0, stream>>>(x, xb, (S * D) / 4);
    cvt_bf16<<<dim3(4096), dim3(256), 0, stream>>>(wq, Wqkvb,                   (D * D) / 4);
    cvt_bf16<<<dim3(4096), dim3(256), 0, stream>>>(wk, Wqkvb + (size_t)D * D,   (D * D) / 4);
    cvt_bf16<<<dim3(4096), dim3(256), 0, stream>>>(wv, Wqkvb + 2 * (size_t)D * D, (D * D) / 4);
    cvt_bf16<<<dim3(4096), dim3(256), 0, stream>>>(wo, Wob, (D * D) / 4);

    gemm_nt<0><<<dim3(48, 32), dim3(256), 0, stream>>>(xb, Wqkvb, Qb, Kb, Vb);
    rmsnorm_qk<<<dim3(16384, 2), dim3(256), 0, stream>>>(Qb, Kb, qw, kw);
    transpose_v<<<dim3(32, 64), dim3(256), 0, stream>>>(Vb, Vt);
    flash_mfma<<<dim3(64, 16), dim3(256), 0, stream>>>(Qb, Kb, Vt, Ctx);
    gemm_nt<1><<<dim3(16, 32), dim3(256), 0, stream>>>(Ctx, Wob, out, out, out);
}